// Round 6
// baseline (444.091 us; speedup 1.0000x reference)
//
#include <hip/hip_runtime.h>
#include <cstddef>

#define H      128
#define NBATCH 32
#define NN     8192
#define RTOT   (NBATCH*NN) // 262144 rows
#define NLAYER 3
#define BNEPS  1e-5f
#define NSLOT  16
#define NPB    64          // rows per block (divides NN)
#define HS_STRIDE 136      // fp16 elems per LDS row (128 + 8 pad)
#define TAIL_F16  768      // 6*128 fp16 scl/sft at end of d_out
#define HEAD_TILES_A 4093  // head launch A tiles; last 3 tiles via 1-block launch B

typedef _Float16 f16;
typedef __attribute__((ext_vector_type(8))) _Float16 half8;  // 8 fp16 (4 VGPRs)
typedef __attribute__((ext_vector_type(4))) float f32x4;     // MFMA C/D

__device__ __forceinline__ void unpackh8(uint4 pk, float* d) {
    const f16* hp = (const f16*)&pk;
    #pragma unroll
    for (int i = 0; i < 8; ++i) d[i] = (float)hp[i];
}

// ---- B-fragment loader from prepped fp16 Wt[n][k] ----
__device__ __forceinline__ void load_bfrags(
    const f16* __restrict__ Wt, half8 bW[2][4], int colbase, int l15, int quad)
{
    #pragma unroll
    for (int nt = 0; nt < 2; ++nt) {
        int nrow = colbase + nt * 16 + l15;
        #pragma unroll
        for (int ks = 0; ks < 4; ++ks)
            bW[nt][ks] = *((const half8*)(Wt + nrow * 128 + ks * 32 + quad * 8));
    }
}

// ---- conv MFMA core: 64 out rows x (colbase..+32) from 66-row hs tile ----
__device__ __forceinline__ void conv_mfma(
    const f16* __restrict__ hs, const half8 bWl[2][4], const half8 bWn[2][4],
    f32x4 acc[4][2], int l15, int quad)
{
    #pragma unroll
    for (int mt = 0; mt < 4; ++mt)
        #pragma unroll
        for (int nt = 0; nt < 2; ++nt)
            acc[mt][nt] = (f32x4){0.f, 0.f, 0.f, 0.f};
    #pragma unroll
    for (int ks = 0; ks < 4; ++ks) {
        half8 as[4], an[4];
        #pragma unroll
        for (int mt = 0; mt < 4; ++mt) {
            int row = mt * 16 + l15;
            const f16* base = hs + row * HS_STRIDE + ks * 32 + quad * 8;
            half8 hm = *((const half8*)(base + HS_STRIDE));
            half8 hd = *((const half8*)(base));
            half8 hu = *((const half8*)(base + 2 * HS_STRIDE));
            as[mt] = hm;
            an[mt] = hd + hu;
        }
        #pragma unroll
        for (int nt = 0; nt < 2; ++nt)
            #pragma unroll
            for (int mt = 0; mt < 4; ++mt)
                acc[mt][nt] = __builtin_amdgcn_mfma_f32_16x16x32_f16(
                    as[mt], bWl[nt][ks], acc[mt][nt], 0, 0, 0);
        #pragma unroll
        for (int nt = 0; nt < 2; ++nt)
            #pragma unroll
            for (int mt = 0; mt < 4; ++mt)
                acc[mt][nt] = __builtin_amdgcn_mfma_f32_16x16x32_f16(
                    an[mt], bWn[nt][ks], acc[mt][nt], 0, 0, 0);
    }
}

// ---- weight prep: fp32 W[l][k][n] -> fp16 Wt[l][n][k] ----
__global__ __launch_bounds__(256) void k_prep(
    const float* __restrict__ lin_w, const float* __restrict__ nb_w,
    f16* __restrict__ Wlt, f16* __restrict__ Wnt)
{
    int id = blockIdx.x * 256 + threadIdx.x;    // 2*3*128*128
    int mat = id / 49152;
    int r   = id - mat * 49152;
    int l   = r >> 14;
    int r2  = r & 16383;
    int k   = r2 >> 7;
    int n   = r2 & 127;
    const float* src = mat ? nb_w : lin_w;
    f16*         dst = mat ? Wnt  : Wlt;
    dst[l * 16384 + n * 128 + k] = (f16)src[l * 16384 + k * 128 + n];
}

// ---- layer 0: h0 = affine(x) on the fly -> conv0 -> hn0 + stats0 ----
__global__ __launch_bounds__(256) void k_conv0(
    const float* __restrict__ x, const float* __restrict__ ew,
    const float* __restrict__ eb,
    const f16* __restrict__ Wlt, const f16* __restrict__ Wnt,
    const float* __restrict__ bl, const float* __restrict__ bnb,
    const float* __restrict__ mask,
    f16* __restrict__ hn0, float* __restrict__ gst0)
{
    __shared__ __align__(16) f16 smem[66 * HS_STRIDE];  // hs / tr reuse
    __shared__ float xs2[66 * 2], ews[3 * H], msk[NPB];
    f16* hs = smem;
    f16* tr = smem;
    const int t = threadIdx.x, wave = t >> 6, lane = t & 63;
    const int l15 = lane & 15, quad = lane >> 4;
    const int r0 = blockIdx.x * NPB;
    const int batch = r0 / NN, n0 = r0 - batch * NN;
    const int colbase = wave * 32;

    half8 bWl[2][4], bWn[2][4];
    load_bfrags(Wlt, bWl, colbase, l15, quad);
    load_bfrags(Wnt, bWn, colbase, l15, quad);

    for (int i = t; i < 66; i += 256) {
        int n = (n0 + i - 1 + NN) & (NN - 1);
        const float* xp = x + 2 * ((size_t)batch * NN + n);
        xs2[2 * i] = xp[0]; xs2[2 * i + 1] = xp[1];
    }
    for (int c = t; c < H; c += 256) {
        ews[c] = ew[c]; ews[H + c] = ew[H + c]; ews[2 * H + c] = eb[c];
    }
    for (int i = t; i < NPB; i += 256) msk[i] = mask[r0 + i];
    __syncthreads();

    for (int i = t; i < 66 * 16; i += 256) {         // compose h0 tile
        int row = i >> 4, g = i & 15;
        float x0 = xs2[2 * row], x1 = xs2[2 * row + 1];
        f16 o[8];
        #pragma unroll
        for (int e = 0; e < 8; ++e) {
            int c = g * 8 + e;
            o[e] = (f16)fmaf(x1, ews[H + c], fmaf(x0, ews[c], ews[2 * H + c]));
        }
        *((uint4*)(hs + row * HS_STRIDE + g * 8)) = *((const uint4*)o);
    }
    __syncthreads();

    f32x4 acc[4][2];
    conv_mfma(hs, bWl, bWn, acc, l15, quad);
    __syncthreads();

    float s[2] = {0.f, 0.f}, ss[2] = {0.f, 0.f};
    #pragma unroll
    for (int nt = 0; nt < 2; ++nt) {
        int col = colbase + nt * 16 + l15;
        float bsum = bl[col] + bnb[col];
        #pragma unroll
        for (int mt = 0; mt < 4; ++mt)
            #pragma unroll
            for (int reg = 0; reg < 4; ++reg) {
                int lrow = mt * 16 + quad * 4 + reg;
                float v = (acc[mt][nt][reg] + bsum) * msk[lrow];
                tr[lrow * HS_STRIDE + col] = (f16)v;
                s[nt] += v; ss[nt] += v * v;
            }
    }
    #pragma unroll
    for (int nt = 0; nt < 2; ++nt) {
        s[nt]  += __shfl_xor(s[nt], 16);  s[nt]  += __shfl_xor(s[nt], 32);
        ss[nt] += __shfl_xor(ss[nt], 16); ss[nt] += __shfl_xor(ss[nt], 32);
    }
    int slot = blockIdx.x & (NSLOT - 1);
    if (lane < 16)
        #pragma unroll
        for (int nt = 0; nt < 2; ++nt) {
            int col = colbase + nt * 16 + lane;
            atomicAdd(&gst0[slot * 2 * H + col],     s[nt]);
            atomicAdd(&gst0[slot * 2 * H + H + col], ss[nt]);
        }
    __syncthreads();
    for (int i = t; i < 64 * 16; i += 256) {
        int row = i >> 4, g = i & 15;
        *((uint4*)(hn0 + (size_t)(r0 + row) * H + g * 8)) =
            *((const uint4*)(tr + row * HS_STRIDE + g * 8));
    }
}

// ---- layer 1: h1 = h0(x) + relu(BN0(hn0)) on the fly -> conv1 -> hn1 + stats1 ----
__global__ __launch_bounds__(256) void k_conv1(
    const float* __restrict__ x, const float* __restrict__ ew,
    const float* __restrict__ eb, const f16* __restrict__ hn0,
    const f16* __restrict__ Wlt, const f16* __restrict__ Wnt,
    const float* __restrict__ bl, const float* __restrict__ bnb,
    const float* __restrict__ mask,
    const float* __restrict__ gstats, const float* __restrict__ bn_g,
    const float* __restrict__ bn_b,
    f16* __restrict__ hn1, float* __restrict__ gst1)
{
    __shared__ __align__(16) f16 smem[66 * HS_STRIDE];
    __shared__ float xs2[66 * 2], ews[3 * H], sclA[2 * H], msk[NPB];
    f16* hs = smem;
    f16* tr = smem;
    const int t = threadIdx.x, wave = t >> 6, lane = t & 63;
    const int l15 = lane & 15, quad = lane >> 4;
    const int r0 = blockIdx.x * NPB;
    const int batch = r0 / NN, n0 = r0 - batch * NN;
    const int colbase = wave * 32;

    half8 bWl[2][4], bWn[2][4];
    load_bfrags(Wlt, bWl, colbase, l15, quad);
    load_bfrags(Wnt, bWn, colbase, l15, quad);

    for (int c = t; c < H; c += 256) {   // scl0/sft0 from gstats layer0
        float s = 0.f, ss = 0.f;
        #pragma unroll
        for (int i = 0; i < NSLOT; ++i) {
            s += gstats[i * 2 * H + c]; ss += gstats[i * 2 * H + H + c];
        }
        const float invR = 1.f / (float)RTOT;
        float mean = s * invR, var = ss * invR - mean * mean;
        float inv = rsqrtf(var + BNEPS);
        float sc = bn_g[c] * inv;
        sclA[c] = sc; sclA[H + c] = fmaf(-mean, sc, bn_b[c]);
    }
    for (int i = t; i < 66; i += 256) {
        int n = (n0 + i - 1 + NN) & (NN - 1);
        const float* xp = x + 2 * ((size_t)batch * NN + n);
        xs2[2 * i] = xp[0]; xs2[2 * i + 1] = xp[1];
    }
    for (int c = t; c < H; c += 256) {
        ews[c] = ew[c]; ews[H + c] = ew[H + c]; ews[2 * H + c] = eb[c];
    }
    for (int i = t; i < NPB; i += 256) msk[i] = mask[r0 + i];
    __syncthreads();

    for (int i = t; i < 66 * 16; i += 256) {         // compose h1 tile
        int row = i >> 4, g = i & 15;
        int n = (n0 + row - 1 + NN) & (NN - 1);
        uint4 pa = *((const uint4*)(hn0 + ((size_t)batch * NN + n) * H + g * 8));
        float va[8]; unpackh8(pa, va);
        float x0 = xs2[2 * row], x1 = xs2[2 * row + 1];
        f16 o[8];
        #pragma unroll
        for (int e = 0; e < 8; ++e) {
            int c = g * 8 + e;
            float h0 = fmaf(x1, ews[H + c], fmaf(x0, ews[c], ews[2 * H + c]));
            o[e] = (f16)(h0 + fmaxf(fmaf(va[e], sclA[c], sclA[H + c]), 0.f));
        }
        *((uint4*)(hs + row * HS_STRIDE + g * 8)) = *((const uint4*)o);
    }
    __syncthreads();

    f32x4 acc[4][2];
    conv_mfma(hs, bWl, bWn, acc, l15, quad);
    __syncthreads();

    float s[2] = {0.f, 0.f}, ss[2] = {0.f, 0.f};
    #pragma unroll
    for (int nt = 0; nt < 2; ++nt) {
        int col = colbase + nt * 16 + l15;
        float bsum = bl[col] + bnb[col];
        #pragma unroll
        for (int mt = 0; mt < 4; ++mt)
            #pragma unroll
            for (int reg = 0; reg < 4; ++reg) {
                int lrow = mt * 16 + quad * 4 + reg;
                float v = (acc[mt][nt][reg] + bsum) * msk[lrow];
                tr[lrow * HS_STRIDE + col] = (f16)v;
                s[nt] += v; ss[nt] += v * v;
            }
    }
    #pragma unroll
    for (int nt = 0; nt < 2; ++nt) {
        s[nt]  += __shfl_xor(s[nt], 16);  s[nt]  += __shfl_xor(s[nt], 32);
        ss[nt] += __shfl_xor(ss[nt], 16); ss[nt] += __shfl_xor(ss[nt], 32);
    }
    int slot = blockIdx.x & (NSLOT - 1);
    if (lane < 16)
        #pragma unroll
        for (int nt = 0; nt < 2; ++nt) {
            int col = colbase + nt * 16 + lane;
            atomicAdd(&gst1[slot * 2 * H + col],     s[nt]);
            atomicAdd(&gst1[slot * 2 * H + H + col], ss[nt]);
        }
    __syncthreads();
    for (int i = t; i < 64 * 16; i += 256) {
        int row = i >> 4, g = i & 15;
        *((uint4*)(hn1 + (size_t)(r0 + row) * H + g * 8)) =
            *((const uint4*)(tr + row * HS_STRIDE + g * 8));
    }
}

// ---- layer 2 stats only: compose h2 -> conv2 -> stats2 (no writes) ----
__global__ __launch_bounds__(256) void k_stats2(
    const float* __restrict__ x, const float* __restrict__ ew,
    const float* __restrict__ eb, const f16* __restrict__ hn0,
    const f16* __restrict__ hn1,
    const f16* __restrict__ Wlt, const f16* __restrict__ Wnt,
    const float* __restrict__ bl, const float* __restrict__ bnb,
    const float* __restrict__ mask,
    const float* __restrict__ gstats, const float* __restrict__ bn_g,
    const float* __restrict__ bn_b, float* __restrict__ gst2)
{
    __shared__ __align__(16) f16 hs[66 * HS_STRIDE];
    __shared__ float xs2[66 * 2], ews[3 * H], sclA[4 * H], msk[NPB];
    const int t = threadIdx.x, wave = t >> 6, lane = t & 63;
    const int l15 = lane & 15, quad = lane >> 4;
    const int r0 = blockIdx.x * NPB;
    const int batch = r0 / NN, n0 = r0 - batch * NN;
    const int colbase = wave * 32;

    half8 bWl[2][4], bWn[2][4];
    load_bfrags(Wlt, bWl, colbase, l15, quad);
    load_bfrags(Wnt, bWn, colbase, l15, quad);

    for (int c = t; c < H; c += 256) {   // scl/sft for layers 0,1
        const float invR = 1.f / (float)RTOT;
        #pragma unroll
        for (int l = 0; l < 2; ++l) {
            const float* ga = gstats + l * NSLOT * 2 * H;
            float s = 0.f, ss = 0.f;
            #pragma unroll
            for (int i = 0; i < NSLOT; ++i) {
                s += ga[i * 2 * H + c]; ss += ga[i * 2 * H + H + c];
            }
            float mean = s * invR, var = ss * invR - mean * mean;
            float inv = rsqrtf(var + BNEPS);
            float sc = bn_g[l * H + c] * inv;
            sclA[l * 2 * H + c] = sc;
            sclA[l * 2 * H + H + c] = fmaf(-mean, sc, bn_b[l * H + c]);
        }
    }
    for (int i = t; i < 66; i += 256) {
        int n = (n0 + i - 1 + NN) & (NN - 1);
        const float* xp = x + 2 * ((size_t)batch * NN + n);
        xs2[2 * i] = xp[0]; xs2[2 * i + 1] = xp[1];
    }
    for (int c = t; c < H; c += 256) {
        ews[c] = ew[c]; ews[H + c] = ew[H + c]; ews[2 * H + c] = eb[c];
    }
    for (int i = t; i < NPB; i += 256) msk[i] = mask[r0 + i];
    __syncthreads();

    for (int i = t; i < 66 * 16; i += 256) {         // compose h2 tile
        int row = i >> 4, g = i & 15;
        int n = (n0 + row - 1 + NN) & (NN - 1);
        size_t off = ((size_t)batch * NN + n) * H + g * 8;
        uint4 pa = *((const uint4*)(hn0 + off));
        uint4 pb = *((const uint4*)(hn1 + off));
        float va[8], vb[8]; unpackh8(pa, va); unpackh8(pb, vb);
        float x0 = xs2[2 * row], x1 = xs2[2 * row + 1];
        f16 o[8];
        #pragma unroll
        for (int e = 0; e < 8; ++e) {
            int c = g * 8 + e;
            float h0 = fmaf(x1, ews[H + c], fmaf(x0, ews[c], ews[2 * H + c]));
            float h1 = h0 + fmaxf(fmaf(va[e], sclA[c],         sclA[H + c]),     0.f);
            o[e] = (f16)(h1 + fmaxf(fmaf(vb[e], sclA[2 * H + c], sclA[3 * H + c]), 0.f));
        }
        *((uint4*)(hs + row * HS_STRIDE + g * 8)) = *((const uint4*)o);
    }
    __syncthreads();

    f32x4 acc[4][2];
    conv_mfma(hs, bWl, bWn, acc, l15, quad);

    float s[2] = {0.f, 0.f}, ss[2] = {0.f, 0.f};
    #pragma unroll
    for (int nt = 0; nt < 2; ++nt) {
        int col = colbase + nt * 16 + l15;
        float bsum = bl[col] + bnb[col];
        #pragma unroll
        for (int mt = 0; mt < 4; ++mt)
            #pragma unroll
            for (int reg = 0; reg < 4; ++reg) {
                int lrow = mt * 16 + quad * 4 + reg;
                float v = (acc[mt][nt][reg] + bsum) * msk[lrow];
                s[nt] += v; ss[nt] += v * v;
            }
    }
    #pragma unroll
    for (int nt = 0; nt < 2; ++nt) {
        s[nt]  += __shfl_xor(s[nt], 16);  s[nt]  += __shfl_xor(s[nt], 32);
        ss[nt] += __shfl_xor(ss[nt], 16); ss[nt] += __shfl_xor(ss[nt], 32);
    }
    int slot = blockIdx.x & (NSLOT - 1);
    if (lane < 16)
        #pragma unroll
        for (int nt = 0; nt < 2; ++nt) {
            int col = colbase + nt * 16 + lane;
            atomicAdd(&gst2[slot * 2 * H + col],     s[nt]);
            atomicAdd(&gst2[slot * 2 * H + H + col], ss[nt]);
        }
}

// ---- finalize all 3 layers' scl/sft -> fp16 tail of d_out ----
__global__ void k_finalize(const float* __restrict__ gstats,
                           const float* __restrict__ bn_g,
                           const float* __restrict__ bn_b,
                           f16* __restrict__ tail)
{
    int c = threadIdx.x;   // H threads
    const float invR = 1.f / (float)RTOT;
    for (int l = 0; l < NLAYER; ++l) {
        const float* ga = gstats + l * NSLOT * 2 * H;
        float s = 0.f, ss = 0.f;
        for (int i = 0; i < NSLOT; ++i) {
            s += ga[i * 2 * H + c]; ss += ga[i * 2 * H + H + c];
        }
        float mean = s * invR, var = ss * invR - mean * mean;
        float inv = rsqrtf(var + BNEPS);
        float sc = bn_g[l * H + c] * inv;
        tail[l * 2 * H + c]     = (f16)sc;
        tail[l * 2 * H + H + c] = (f16)fmaf(-mean, sc, bn_b[l * H + c]);
    }
}

// ---- head: compose h2 -> conv2 -> BN2+res -> h3 -> (relu(h3@W1+b1))@W2+b2 ----
// Launch A: grid HEAD_TILES_A, tile0=0, ntiles=1.  Launch B (after A): grid 1,
// tile0=HEAD_TILES_A, ntiles=3 — covers the rows whose d_out bytes hold the
// scl/sft tail (single block: reads tail into LDS before overwriting).
__global__ __launch_bounds__(256) void k_head(
    const float* __restrict__ x, const float* __restrict__ ew,
    const float* __restrict__ eb, const f16* __restrict__ hn0,
    const f16* __restrict__ hn1,
    const float* __restrict__ Wl2, const float* __restrict__ Wn2,  // fp32 layer-2 weights (d_in)
    const float* __restrict__ bl, const float* __restrict__ bnb,
    const float* __restrict__ mask, const f16* __restrict__ tail,
    const float* __restrict__ W1, const float* __restrict__ b1,
    const float* __restrict__ W2, const float* __restrict__ b2,
    float* __restrict__ out, int tile0, int ntiles)
{
    __shared__ __align__(16) f16 hs [66 * HS_STRIDE];
    __shared__ __align__(16) f16 h3t[64 * HS_STRIDE];
    __shared__ __align__(16) f16 w1t[64 * HS_STRIDE];
    __shared__ float xs2[66 * 2], ews[3 * H], sclA[6 * H], msk[NPB];
    const int t = threadIdx.x, wave = t >> 6, lane = t & 63;
    const int l15 = lane & 15, quad = lane >> 4;
    const int colbase = wave * 32;

    // conv2 B-fragments straight from fp32 inputs (no d_out read)
    half8 bWl[2][4], bWn[2][4];
    #pragma unroll
    for (int nt = 0; nt < 2; ++nt) {
        int n = colbase + nt * 16 + l15;
        #pragma unroll
        for (int ks = 0; ks < 4; ++ks) {
            half8 vl, vn;
            #pragma unroll
            for (int j = 0; j < 8; ++j) {
                int k = ks * 32 + quad * 8 + j;
                vl[j] = (f16)Wl2[k * H + n];
                vn[j] = (f16)Wn2[k * H + n];
            }
            bWl[nt][ks] = vl; bWn[nt][ks] = vn;
        }
    }

    for (int i = t; i < TAIL_F16; i += 256) sclA[i] = (float)tail[i];
    for (int c = t; c < H; c += 256) {
        ews[c] = ew[c]; ews[H + c] = ew[H + c]; ews[2 * H + c] = eb[c];
    }
    for (int i = t; i < H * 64; i += 256) {   // W1[k][n] fp32 -> w1t[n][k] fp16
        int k = i >> 6, n = i & 63;
        w1t[n * HS_STRIDE + k] = (f16)W1[i];
    }
    __syncthreads();

    for (int tt = 0; tt < ntiles; ++tt) {
        const int tile = tile0 + blockIdx.x * ntiles + tt;
        const int r0 = tile * NPB;
        const int batch = r0 / NN, n0 = r0 - batch * NN;

        for (int i = t; i < 66; i += 256) {
            int n = (n0 + i - 1 + NN) & (NN - 1);
            const float* xp = x + 2 * ((size_t)batch * NN + n);
            xs2[2 * i] = xp[0]; xs2[2 * i + 1] = xp[1];
        }
        for (int i = t; i < NPB; i += 256) msk[i] = mask[r0 + i];
        __syncthreads();

        for (int i = t; i < 66 * 16; i += 256) {     // compose h2 tile
            int row = i >> 4, g = i & 15;
            int n = (n0 + row - 1 + NN) & (NN - 1);
            size_t off = ((size_t)batch * NN + n) * H + g * 8;
            uint4 pa = *((const uint4*)(hn0 + off));
            uint4 pb = *((const uint4*)(hn1 + off));
            float va[8], vb[8]; unpackh8(pa, va); unpackh8(pb, vb);
            float x0 = xs2[2 * row], x1 = xs2[2 * row + 1];
            f16 o[8];
            #pragma unroll
            for (int e = 0; e < 8; ++e) {
                int c = g * 8 + e;
                float h0 = fmaf(x1, ews[H + c], fmaf(x0, ews[c], ews[2 * H + c]));
                float h1 = h0 + fmaxf(fmaf(va[e], sclA[c],         sclA[H + c]),     0.f);
                o[e] = (f16)(h1 + fmaxf(fmaf(vb[e], sclA[2 * H + c], sclA[3 * H + c]), 0.f));
            }
            *((uint4*)(hs + row * HS_STRIDE + g * 8)) = *((const uint4*)o);
        }
        __syncthreads();

        f32x4 acc[4][2];
        conv_mfma(hs, bWl, bWn, acc, l15, quad);

        // BN2 + relu + residual -> h3 tile (reads hs, writes h3t)
        #pragma unroll
        for (int nt = 0; nt < 2; ++nt) {
            int col = colbase + nt * 16 + l15;
            float bsum = bl[col] + bnb[col];
            float sc2 = sclA[4 * H + col], sf2 = sclA[5 * H + col];
            #pragma unroll
            for (int mt = 0; mt < 4; ++mt)
                #pragma unroll
                for (int reg = 0; reg < 4; ++reg) {
                    int lrow = mt * 16 + quad * 4 + reg;
                    float hnv = (acc[mt][nt][reg] + bsum) * msk[lrow];
                    float h2v = (float)hs[(lrow + 1) * HS_STRIDE + col];
                    h3t[lrow * HS_STRIDE + col] =
                        (f16)(h2v + fmaxf(fmaf(hnv, sc2, sf2), 0.f));
                }
        }
        __syncthreads();

        // head GEMM: 16 rows per wave from h3t, 64 cols from w1t
        f32x4 acc2[4];
        #pragma unroll
        for (int nt = 0; nt < 4; ++nt) acc2[nt] = (f32x4){0.f, 0.f, 0.f, 0.f};
        #pragma unroll
        for (int ks = 0; ks < 4; ++ks) {
            half8 a = *((const half8*)(h3t + (wave * 16 + l15) * HS_STRIDE + ks * 32 + quad * 8));
            #pragma unroll
            for (int nt = 0; nt < 4; ++nt) {
                half8 b = *((const half8*)(w1t + (nt * 16 + l15) * HS_STRIDE + ks * 32 + quad * 8));
                acc2[nt] = __builtin_amdgcn_mfma_f32_16x16x32_f16(a, b, acc2[nt], 0, 0, 0);
            }
        }
        float p0[4] = {0,0,0,0}, p1[4] = {0,0,0,0};
        #pragma unroll
        for (int nt = 0; nt < 4; ++nt) {
            int col = nt * 16 + l15;
            float bb = b1[col];
            float wa = W2[2 * col], wb = W2[2 * col + 1];
            #pragma unroll
            for (int reg = 0; reg < 4; ++reg) {
                float v = fmaxf(acc2[nt][reg] + bb, 0.f);
                p0[reg] = fmaf(v, wa, p0[reg]);
                p1[reg] = fmaf(v, wb, p1[reg]);
            }
        }
        #pragma unroll
        for (int reg = 0; reg < 4; ++reg) {
            p0[reg] += __shfl_xor(p0[reg], 1); p0[reg] += __shfl_xor(p0[reg], 2);
            p0[reg] += __shfl_xor(p0[reg], 4); p0[reg] += __shfl_xor(p0[reg], 8);
            p1[reg] += __shfl_xor(p1[reg], 1); p1[reg] += __shfl_xor(p1[reg], 2);
            p1[reg] += __shfl_xor(p1[reg], 4); p1[reg] += __shfl_xor(p1[reg], 8);
        }
        if (l15 == 0)
            #pragma unroll
            for (int reg = 0; reg < 4; ++reg) {
                int gr = r0 + wave * 16 + quad * 4 + reg;
                float m = mask[gr];
                float2 o;
                o.x = (p0[reg] + b2[0]) * m;
                o.y = (p1[reg] + b2[1]) * m;
                *((float2*)(out + 2 * gr)) = o;
            }
        __syncthreads();   // tile LDS reuse
    }
}

extern "C" void kernel_launch(void* const* d_in, const int* in_sizes, int n_in,
                              void* d_out, int out_size, void* d_ws, size_t ws_size,
                              hipStream_t stream)
{
    const float* x     = (const float*)d_in[0];
    const float* mask  = (const float*)d_in[1];
    const float* emb_w = (const float*)d_in[2];
    const float* emb_b = (const float*)d_in[3];
    const float* lin_w = (const float*)d_in[4];
    const float* lin_b = (const float*)d_in[5];
    const float* nb_w  = (const float*)d_in[6];
    const float* nb_b  = (const float*)d_in[7];
    const float* bn_g  = (const float*)d_in[8];
    const float* bn_b  = (const float*)d_in[9];
    const float* o1w   = (const float*)d_in[10];
    const float* o1b   = (const float*)d_in[11];
    const float* o2w   = (const float*)d_in[12];
    const float* o2b   = (const float*)d_in[13];
    float* out = (float*)d_out;

    // Workspace: hn0 (fp16, 64 MiB) + hn1 (fp16, 64 MiB) = 128 MiB (proven safe).
    char* ws = (char*)d_ws;
    f16* hn0 = (f16*)ws;
    f16* hn1 = (f16*)(ws + (size_t)RTOT * H * 2);

    // d_out scratch (consumed before the head writes those bytes):
    //   floats [0,12288): gstats (3 layers x 16 slots x 256)
    //   float offset 65536 (byte 256K): fp16 Wlt/Wnt (3 layers each)
    //   last TAIL_F16 fp16: packed scl/sft for all 3 layers (head reads only this;
    //   its rows are written solely by the 1-block launch B, which runs after A).
    float* gst = (float*)d_out;
    f16* Wlt  = (f16*)((float*)d_out + 65536);
    f16* Wnt  = Wlt + NLAYER * H * H;
    f16* tail = (f16*)d_out + ((size_t)RTOT * 2 * 2 - TAIL_F16);  // f16 units

    hipMemsetAsync(gst, 0, NLAYER * NSLOT * 2 * H * sizeof(float), stream);
    k_prep<<<384, 256, 0, stream>>>(lin_w, nb_w, Wlt, Wnt);

    k_conv0<<<RTOT / NPB, 256, 0, stream>>>(
        x, emb_w, emb_b, Wlt, Wnt, lin_b, nb_b, mask, hn0, gst);
    k_conv1<<<RTOT / NPB, 256, 0, stream>>>(
        x, emb_w, emb_b, hn0, Wlt + H * H, Wnt + H * H,
        lin_b + H, nb_b + H, mask, gst, bn_g, bn_b,
        hn1, gst + NSLOT * 2 * H);
    k_stats2<<<RTOT / NPB, 256, 0, stream>>>(
        x, emb_w, emb_b, hn0, hn1, Wlt + 2 * H * H, Wnt + 2 * H * H,
        lin_b + 2 * H, nb_b + 2 * H, mask, gst, bn_g, bn_b,
        gst + 2 * NSLOT * 2 * H);
    k_finalize<<<1, H, 0, stream>>>(gst, bn_g, bn_b, tail);

    k_head<<<HEAD_TILES_A, 256, 0, stream>>>(
        x, emb_w, emb_b, hn0, hn1, lin_w + 2 * H * H, nb_w + 2 * H * H,
        lin_b + 2 * H, nb_b + 2 * H, mask, tail,
        o1w, o1b, o2w, o2b, out, 0, 1);
    k_head<<<1, 256, 0, stream>>>(
        x, emb_w, emb_b, hn0, hn1, lin_w + 2 * H * H, nb_w + 2 * H * H,
        lin_b + 2 * H, nb_b + 2 * H, mask, tail,
        o1w, o1b, o2w, o2b, out, HEAD_TILES_A, 3);
}

// Round 8
// 352.602 us; speedup vs baseline: 1.2595x; 1.2595x over previous
//
#include <hip/hip_runtime.h>
#include <cstddef>

#define H      128
#define NBATCH 32
#define NN     8192
#define RTOT   (NBATCH*NN) // 262144 rows
#define NLAYER 3
#define BNEPS  1e-5f
#define NSLOT  16
#define CNPB   128         // rows per conv block (divides NN)
#define HNPB   64          // rows per head block
#define HS_STRIDE 136      // fp16 elems per LDS row (128 + 8 pad)

typedef _Float16 f16;
typedef __attribute__((ext_vector_type(8))) _Float16 half8;  // 8 fp16 (4 VGPRs)
typedef __attribute__((ext_vector_type(4))) float f32x4;     // MFMA C/D

__device__ __forceinline__ void unpackh8(uint4 pk, float* d) {
    const f16* hp = (const f16*)&pk;
    #pragma unroll
    for (int i = 0; i < 8; ++i) d[i] = (float)hp[i];
}
__device__ __forceinline__ uint4 packh8(const float* s) {
    uint4 pk;
    f16* hp = (f16*)&pk;
    #pragma unroll
    for (int i = 0; i < 8; ++i) hp[i] = (f16)s[i];
    return pk;
}

__device__ __forceinline__ void load_bfrags(
    const f16* __restrict__ Wt, half8 bW[2][4], int colbase, int l15, int quad)
{
    #pragma unroll
    for (int nt = 0; nt < 2; ++nt) {
        int nrow = colbase + nt * 16 + l15;
        #pragma unroll
        for (int ks = 0; ks < 4; ++ks)
            bW[nt][ks] = *((const half8*)(Wt + nrow * 128 + ks * 32 + quad * 8));
    }
}

// conv MFMA core over a 130-row hs tile: 128 out rows x 32 cols per wave
__device__ __forceinline__ void conv_mfma8(
    const f16* __restrict__ hs, const half8 bWl[2][4], const half8 bWn[2][4],
    f32x4 acc[8][2], int l15, int quad)
{
    #pragma unroll
    for (int mt = 0; mt < 8; ++mt) {
        acc[mt][0] = (f32x4){0.f, 0.f, 0.f, 0.f};
        acc[mt][1] = (f32x4){0.f, 0.f, 0.f, 0.f};
    }
    #pragma unroll
    for (int ks = 0; ks < 4; ++ks) {
        #pragma unroll
        for (int mt = 0; mt < 8; ++mt) {
            int row = mt * 16 + l15;
            const f16* base = hs + row * HS_STRIDE + ks * 32 + quad * 8;
            half8 hm = *((const half8*)(base + HS_STRIDE));       // center row
            half8 hd = *((const half8*)(base));                   // row-1
            half8 hu = *((const half8*)(base + 2 * HS_STRIDE));   // row+1
            half8 an = hd + hu;
            acc[mt][0] = __builtin_amdgcn_mfma_f32_16x16x32_f16(hm, bWl[0][ks], acc[mt][0], 0, 0, 0);
            acc[mt][1] = __builtin_amdgcn_mfma_f32_16x16x32_f16(hm, bWl[1][ks], acc[mt][1], 0, 0, 0);
            acc[mt][0] = __builtin_amdgcn_mfma_f32_16x16x32_f16(an, bWn[0][ks], acc[mt][0], 0, 0, 0);
            acc[mt][1] = __builtin_amdgcn_mfma_f32_16x16x32_f16(an, bWn[1][ks], acc[mt][1], 0, 0, 0);
        }
    }
}

// ---- weight prep: fp32 W[l][k][n] -> fp16 Wt[l][n][k] ----
__global__ __launch_bounds__(256) void k_prep(
    const float* __restrict__ lin_w, const float* __restrict__ nb_w,
    f16* __restrict__ Wlt, f16* __restrict__ Wnt)
{
    int id = blockIdx.x * 256 + threadIdx.x;
    int mat = id / 49152;
    int r   = id - mat * 49152;
    int l   = r >> 14;
    int r2  = r & 16383;
    int k   = r2 >> 7;
    int n   = r2 & 127;
    const float* src = mat ? nb_w : lin_w;
    f16*         dst = mat ? Wnt  : Wlt;
    dst[l * 16384 + n * 128 + k] = (f16)src[l * 16384 + k * 128 + n];
}

// ---- shared conv epilogue+writeback (tr aliases hs rows 0..127) ----
__device__ __forceinline__ void conv_epilogue(
    f32x4 acc[8][2], const float bsum[2], const float* __restrict__ msk,
    f16* __restrict__ tr, f16* __restrict__ hnb, float* __restrict__ gstats,
    int r0, int colbase, int l15, int quad, int lane, int t, int slot)
{
    float s[2] = {0.f, 0.f}, ss[2] = {0.f, 0.f};
    #pragma unroll
    for (int nt = 0; nt < 2; ++nt) {
        int col = colbase + nt * 16 + l15;
        #pragma unroll
        for (int mt = 0; mt < 8; ++mt)
            #pragma unroll
            for (int reg = 0; reg < 4; ++reg) {
                int lrow = mt * 16 + quad * 4 + reg;
                float v = (acc[mt][nt][reg] + bsum[nt]) * msk[lrow];
                tr[lrow * HS_STRIDE + col] = (f16)v;
                s[nt] += v; ss[nt] += v * v;
            }
    }
    #pragma unroll
    for (int nt = 0; nt < 2; ++nt) {
        s[nt]  += __shfl_xor(s[nt], 16);  s[nt]  += __shfl_xor(s[nt], 32);
        ss[nt] += __shfl_xor(ss[nt], 16); ss[nt] += __shfl_xor(ss[nt], 32);
    }
    if (lane < 16)
        #pragma unroll
        for (int nt = 0; nt < 2; ++nt) {
            int col = colbase + nt * 16 + lane;
            atomicAdd(&gstats[slot * 2 * H + col],     s[nt]);
            atomicAdd(&gstats[slot * 2 * H + H + col], ss[nt]);
        }
    __syncthreads();
    for (int i = t; i < CNPB * 16; i += 256) {
        int row = i >> 4, g = i & 15;
        *((uint4*)(hnb + (size_t)(r0 + row) * H + g * 8)) =
            *((const uint4*)(tr + row * HS_STRIDE + g * 8));
    }
}

// ---- layer 0 conv: compose h0 = affine(x) in LDS -> conv -> hnb + stats ----
__global__ __launch_bounds__(256) void k_conv0f(
    const float* __restrict__ x, const float* __restrict__ ew,
    const float* __restrict__ eb,
    const f16* __restrict__ Wlt, const f16* __restrict__ Wnt,
    const float* __restrict__ bl, const float* __restrict__ bnb,
    const float* __restrict__ mask,
    f16* __restrict__ hnb, float* __restrict__ gstats)
{
    __shared__ __align__(16) f16 smem[(CNPB + 2) * HS_STRIDE];
    __shared__ float ews[3 * H], msk[CNPB];
    f16* hs = smem;
    f16* tr = smem;
    const int t = threadIdx.x, lane = t & 63;
    const int l15 = lane & 15, quad = lane >> 4;
    const int colbase = (t >> 6) * 32;
    const int r0 = blockIdx.x * CNPB;
    const int batch = r0 >> 13, n0 = r0 & (NN - 1);

    half8 bWl[2][4], bWn[2][4];
    load_bfrags(Wlt, bWl, colbase, l15, quad);
    load_bfrags(Wnt, bWn, colbase, l15, quad);
    float bsum[2];
    #pragma unroll
    for (int nt = 0; nt < 2; ++nt) {
        int col = colbase + nt * 16 + l15;
        bsum[nt] = bl[col] + bnb[col];
    }
    for (int c = t; c < H; c += 256) {
        ews[c] = ew[c]; ews[H + c] = ew[H + c]; ews[2 * H + c] = eb[c];
    }
    if (t < CNPB) msk[t] = mask[r0 + t];
    __syncthreads();

    for (int i = t; i < (CNPB + 2) * 16; i += 256) {
        int row = i >> 4, g = i & 15;
        int n = (n0 + row - 1 + NN) & (NN - 1);
        const float* xp = x + 2 * ((size_t)batch * NN + n);
        float x0 = xp[0], x1 = xp[1];
        f16 o[8];
        #pragma unroll
        for (int e = 0; e < 8; ++e) {
            int c = g * 8 + e;
            o[e] = (f16)fmaf(x1, ews[H + c], fmaf(x0, ews[c], ews[2 * H + c]));
        }
        *((uint4*)(hs + row * HS_STRIDE + g * 8)) = *((const uint4*)o);
    }
    __syncthreads();

    f32x4 acc[8][2];
    conv_mfma8(hs, bWl, bWn, acc, l15, quad);
    __syncthreads();

    conv_epilogue(acc, bsum, msk, tr, hnb, gstats,
                  r0, colbase, l15, quad, lane, t, blockIdx.x & (NSLOT - 1));
}

// ---- generic conv (layers 1,2): stage hb tile -> conv -> hnb + stats ----
__global__ __launch_bounds__(256) void k_conv(
    const f16* __restrict__ hb,
    const f16* __restrict__ Wlt, const f16* __restrict__ Wnt,
    const float* __restrict__ bl, const float* __restrict__ bnb,
    const float* __restrict__ mask,
    f16* __restrict__ hnb, float* __restrict__ gstats)
{
    __shared__ __align__(16) f16 smem[(CNPB + 2) * HS_STRIDE];
    __shared__ float msk[CNPB];
    f16* hs = smem;
    f16* tr = smem;
    const int t = threadIdx.x, lane = t & 63;
    const int l15 = lane & 15, quad = lane >> 4;
    const int colbase = (t >> 6) * 32;
    const int r0 = blockIdx.x * CNPB;
    const int batch = r0 >> 13, n0 = r0 & (NN - 1);

    half8 bWl[2][4], bWn[2][4];
    load_bfrags(Wlt, bWl, colbase, l15, quad);
    load_bfrags(Wnt, bWn, colbase, l15, quad);
    float bsum[2];
    #pragma unroll
    for (int nt = 0; nt < 2; ++nt) {
        int col = colbase + nt * 16 + l15;
        bsum[nt] = bl[col] + bnb[col];
    }
    if (t < CNPB) msk[t] = mask[r0 + t];

    for (int i = t; i < (CNPB + 2) * 16; i += 256) {
        int row = i >> 4, g = i & 15;
        int n = (n0 + row - 1 + NN) & (NN - 1);
        *((uint4*)(hs + row * HS_STRIDE + g * 8)) =
            *((const uint4*)(hb + ((size_t)(batch * NN + n)) * H + g * 8));
    }
    __syncthreads();

    f32x4 acc[8][2];
    conv_mfma8(hs, bWl, bWn, acc, l15, quad);
    __syncthreads();

    conv_epilogue(acc, bsum, msk, tr, hnb, gstats,
                  r0, colbase, l15, quad, lane, t, blockIdx.x & (NSLOT - 1));
}

// ---- norm0: hb = affine(x) + relu(BN0(hnb)), BN finalize inlined ----
__global__ __launch_bounds__(256) void k_norm0(
    const float* __restrict__ x, const float* __restrict__ ew,
    const float* __restrict__ eb, const f16* __restrict__ hnb,
    const float* __restrict__ gstats, const float* __restrict__ bn_g,
    const float* __restrict__ bn_b, f16* __restrict__ hb)
{
    __shared__ float scl_s[H], sft_s[H], ews[3 * H];
    const int t = threadIdx.x;
    if (t < H) {
        float s = 0.f, ss = 0.f;
        #pragma unroll
        for (int i = 0; i < NSLOT; ++i) {
            s  += gstats[i * 2 * H + t];
            ss += gstats[i * 2 * H + H + t];
        }
        const float invR = 1.f / (float)RTOT;
        float mean = s * invR;
        float var  = ss * invR - mean * mean;
        float inv  = rsqrtf(var + BNEPS);
        float sc   = bn_g[t] * inv;
        scl_s[t] = sc;
        sft_s[t] = fmaf(-mean, sc, bn_b[t]);
        ews[t] = ew[t]; ews[H + t] = ew[H + t]; ews[2 * H + t] = eb[t];
    }
    __syncthreads();

    for (size_t idx = (size_t)blockIdx.x * 256 + t; idx < (size_t)RTOT * 16;
         idx += (size_t)gridDim.x * 256) {
        size_t row = idx >> 4;
        int g = idx & 15;
        float x0 = x[2 * row], x1 = x[2 * row + 1];
        uint4 pn = *((const uint4*)(hnb + row * H + g * 8));
        float vn[8], vh[8];
        unpackh8(pn, vn);
        #pragma unroll
        for (int e = 0; e < 8; ++e) {
            int c = g * 8 + e;
            float h0 = fmaf(x1, ews[H + c], fmaf(x0, ews[c], ews[2 * H + c]));
            vh[e] = h0 + fmaxf(fmaf(vn[e], scl_s[c], sft_s[c]), 0.f);
        }
        *((uint4*)(hb + row * H + g * 8)) = packh8(vh);
    }
}

// ---- norm (layers 1,2): hb += relu(BN(hnb)), BN finalize inlined ----
__global__ __launch_bounds__(256) void k_norm(
    const f16* __restrict__ hnb, const float* __restrict__ gstats,
    const float* __restrict__ bn_g, const float* __restrict__ bn_b,
    f16* __restrict__ hb)
{
    __shared__ float scl_s[H], sft_s[H];
    const int t = threadIdx.x;
    if (t < H) {
        float s = 0.f, ss = 0.f;
        #pragma unroll
        for (int i = 0; i < NSLOT; ++i) {
            s  += gstats[i * 2 * H + t];
            ss += gstats[i * 2 * H + H + t];
        }
        const float invR = 1.f / (float)RTOT;
        float mean = s * invR;
        float var  = ss * invR - mean * mean;
        float inv  = rsqrtf(var + BNEPS);
        float sc   = bn_g[t] * inv;
        scl_s[t] = sc;
        sft_s[t] = fmaf(-mean, sc, bn_b[t]);
    }
    __syncthreads();

    for (size_t idx = (size_t)blockIdx.x * 256 + t; idx < (size_t)RTOT * 16;
         idx += (size_t)gridDim.x * 256) {
        size_t row = idx >> 4;
        int g = idx & 15;
        uint4 pn = *((const uint4*)(hnb + row * H + g * 8));
        uint4 ph = *((const uint4*)(hb  + row * H + g * 8));
        float vn[8], vh[8];
        unpackh8(pn, vn);
        unpackh8(ph, vh);
        #pragma unroll
        for (int e = 0; e < 8; ++e) {
            int c = g * 8 + e;
            vh[e] += fmaxf(fmaf(vn[e], scl_s[c], sft_s[c]), 0.f);
        }
        *((uint4*)(hb + row * H + g * 8)) = packh8(vh);
    }
}

// ---- MFMA head: out = (relu(h@W1 + b1) @ W2 + b2) * m ----
__global__ __launch_bounds__(256) void k_head(
    const f16* __restrict__ hb, const float* __restrict__ W1,
    const float* __restrict__ b1, const float* __restrict__ W2,
    const float* __restrict__ b2, const float* __restrict__ mask,
    float* __restrict__ out)
{
    __shared__ f16 hs [64 * HS_STRIDE];   // h rows, fp16
    __shared__ f16 w1t[64 * HS_STRIDE];   // W1^T [n][k], fp16, padded
    const int t    = threadIdx.x;
    const int wave = t >> 6;
    const int lane = t & 63;
    const int l15  = lane & 15;
    const int quad = lane >> 4;
    const int r0   = blockIdx.x * HNPB;

    for (int i = t; i < 64 * 16; i += 256) {
        int row = i >> 4, g = i & 15;
        *((uint4*)(hs + row * HS_STRIDE + g * 8)) =
            *((const uint4*)(hb + (size_t)(r0 + row) * H + g * 8));
    }
    for (int i = t; i < H * 64; i += 256) {    // W1[k][n] fp32 -> w1t[n][k] fp16
        int k = i >> 6, n = i & 63;
        w1t[n * HS_STRIDE + k] = (f16)W1[i];
    }
    __syncthreads();

    f32x4 acc[4];
    #pragma unroll
    for (int nt = 0; nt < 4; ++nt) acc[nt] = (f32x4){0.f, 0.f, 0.f, 0.f};

    #pragma unroll
    for (int ks = 0; ks < 4; ++ks) {
        half8 a = *((const half8*)(hs + (wave * 16 + l15) * HS_STRIDE + ks * 32 + quad * 8));
        #pragma unroll
        for (int nt = 0; nt < 4; ++nt) {
            half8 b = *((const half8*)(w1t + (nt * 16 + l15) * HS_STRIDE + ks * 32 + quad * 8));
            acc[nt] = __builtin_amdgcn_mfma_f32_16x16x32_f16(a, b, acc[nt], 0, 0, 0);
        }
    }

    float p0[4] = {0,0,0,0}, p1[4] = {0,0,0,0};
    #pragma unroll
    for (int nt = 0; nt < 4; ++nt) {
        int col = nt * 16 + l15;
        float bb = b1[col];
        float wa = W2[2 * col], wb = W2[2 * col + 1];
        #pragma unroll
        for (int reg = 0; reg < 4; ++reg) {
            float v = fmaxf(acc[nt][reg] + bb, 0.f);
            p0[reg] = fmaf(v, wa, p0[reg]);
            p1[reg] = fmaf(v, wb, p1[reg]);
        }
    }
    #pragma unroll
    for (int reg = 0; reg < 4; ++reg) {
        p0[reg] += __shfl_xor(p0[reg], 1); p0[reg] += __shfl_xor(p0[reg], 2);
        p0[reg] += __shfl_xor(p0[reg], 4); p0[reg] += __shfl_xor(p0[reg], 8);
        p1[reg] += __shfl_xor(p1[reg], 1); p1[reg] += __shfl_xor(p1[reg], 2);
        p1[reg] += __shfl_xor(p1[reg], 4); p1[reg] += __shfl_xor(p1[reg], 8);
    }
    if (l15 == 0) {
        #pragma unroll
        for (int reg = 0; reg < 4; ++reg) {
            int gr = r0 + wave * 16 + quad * 4 + reg;
            float m = mask[gr];
            float2 o;
            o.x = (p0[reg] + b2[0]) * m;
            o.y = (p1[reg] + b2[1]) * m;
            *((float2*)(out + 2 * gr)) = o;
        }
    }
}

extern "C" void kernel_launch(void* const* d_in, const int* in_sizes, int n_in,
                              void* d_out, int out_size, void* d_ws, size_t ws_size,
                              hipStream_t stream)
{
    const float* x     = (const float*)d_in[0];
    const float* mask  = (const float*)d_in[1];
    const float* emb_w = (const float*)d_in[2];
    const float* emb_b = (const float*)d_in[3];
    const float* lin_w = (const float*)d_in[4];
    const float* lin_b = (const float*)d_in[5];
    const float* nb_w  = (const float*)d_in[6];
    const float* nb_b  = (const float*)d_in[7];
    const float* bn_g  = (const float*)d_in[8];
    const float* bn_b  = (const float*)d_in[9];
    const float* o1w   = (const float*)d_in[10];
    const float* o1b   = (const float*)d_in[11];
    const float* o2w   = (const float*)d_in[12];
    const float* o2b   = (const float*)d_in[13];
    float* out = (float*)d_out;

    // Workspace: hb (fp16, 64 MiB) + hnb (fp16, 64 MiB) = 128 MiB (proven safe).
    char* ws = (char*)d_ws;
    f16* hb  = (f16*)ws;
    f16* hnb = (f16*)(ws + (size_t)RTOT * H * 2);

    // d_out scratch (consumed by conv/norm only — k_head reads no d_out scratch,
    // so its out writes can never race with scratch readers):
    float* gst = (float*)d_out;                  // 3 * NSLOT * 2 * H floats
    f16* Wlt = (f16*)((float*)d_out + 65536);    // 3*128*128 fp16
    f16* Wnt = Wlt + NLAYER * H * H;

    hipMemsetAsync(gst, 0, NLAYER * NSLOT * 2 * H * sizeof(float), stream);
    k_prep<<<384, 256, 0, stream>>>(lin_w, nb_w, Wlt, Wnt);

    // layer 0 (h0 composed from x on the fly; no embed kernel, no hb read)
    k_conv0f<<<RTOT / CNPB, 256, 0, stream>>>(
        x, emb_w, emb_b, Wlt, Wnt, lin_b, nb_b, mask, hnb, gst);
    k_norm0<<<2048, 256, 0, stream>>>(
        x, emb_w, emb_b, hnb, gst, bn_g, bn_b, hb);

    // layers 1, 2
    for (int i = 1; i < NLAYER; ++i) {
        k_conv<<<RTOT / CNPB, 256, 0, stream>>>(
            hb, Wlt + i * H * H, Wnt + i * H * H,
            lin_b + i * H, nb_b + i * H, mask,
            hnb, gst + i * NSLOT * 2 * H);
        k_norm<<<2048, 256, 0, stream>>>(
            hnb, gst + i * NSLOT * 2 * H, bn_g + i * H, bn_b + i * H, hb);
    }
    k_head<<<RTOT / HNPB, 256, 0, stream>>>(hb, o1w, o1b, o2w, o2b, mask, out);
}

// Round 9
// 342.897 us; speedup vs baseline: 1.2951x; 1.0283x over previous
//
#include <hip/hip_runtime.h>
#include <cstddef>

#define H      128
#define NBATCH 32
#define NN     8192
#define RTOT   (NBATCH*NN) // 262144 rows
#define NLAYER 3
#define BNEPS  1e-5f
#define NSLOT  16
#define CNPB   128         // rows per conv/norm tile (divides NN)
#define HNPB   64          // rows per head block
#define HS_STRIDE 136      // fp16 elems per LDS row (128 + 8 pad)

typedef _Float16 f16;
typedef __attribute__((ext_vector_type(8))) _Float16 half8;  // 8 fp16 (4 VGPRs)
typedef __attribute__((ext_vector_type(4))) float f32x4;     // MFMA C/D

__device__ __forceinline__ void unpackh8(uint4 pk, float* d) {
    const f16* hp = (const f16*)&pk;
    #pragma unroll
    for (int i = 0; i < 8; ++i) d[i] = (float)hp[i];
}
__device__ __forceinline__ uint4 packh8(const float* s) {
    uint4 pk;
    f16* hp = (f16*)&pk;
    #pragma unroll
    for (int i = 0; i < 8; ++i) hp[i] = (f16)s[i];
    return pk;
}

__device__ __forceinline__ void load_bfrags(
    const f16* __restrict__ Wt, half8 bW[2][4], int colbase, int l15, int quad)
{
    #pragma unroll
    for (int nt = 0; nt < 2; ++nt) {
        int nrow = colbase + nt * 16 + l15;
        #pragma unroll
        for (int ks = 0; ks < 4; ++ks)
            bW[nt][ks] = *((const half8*)(Wt + nrow * 128 + ks * 32 + quad * 8));
    }
}

// conv MFMA core over a 130-row hs tile: 128 out rows x 32 cols per wave
__device__ __forceinline__ void conv_mfma8(
    const f16* __restrict__ hs, const half8 bWl[2][4], const half8 bWn[2][4],
    f32x4 acc[8][2], int l15, int quad)
{
    #pragma unroll
    for (int mt = 0; mt < 8; ++mt) {
        acc[mt][0] = (f32x4){0.f, 0.f, 0.f, 0.f};
        acc[mt][1] = (f32x4){0.f, 0.f, 0.f, 0.f};
    }
    #pragma unroll
    for (int ks = 0; ks < 4; ++ks) {
        #pragma unroll
        for (int mt = 0; mt < 8; ++mt) {
            int row = mt * 16 + l15;
            const f16* base = hs + row * HS_STRIDE + ks * 32 + quad * 8;
            half8 hm = *((const half8*)(base + HS_STRIDE));       // center row
            half8 hd = *((const half8*)(base));                   // row-1
            half8 hu = *((const half8*)(base + 2 * HS_STRIDE));   // row+1
            half8 an = hd + hu;
            acc[mt][0] = __builtin_amdgcn_mfma_f32_16x16x32_f16(hm, bWl[0][ks], acc[mt][0], 0, 0, 0);
            acc[mt][1] = __builtin_amdgcn_mfma_f32_16x16x32_f16(hm, bWl[1][ks], acc[mt][1], 0, 0, 0);
            acc[mt][0] = __builtin_amdgcn_mfma_f32_16x16x32_f16(an, bWn[0][ks], acc[mt][0], 0, 0, 0);
            acc[mt][1] = __builtin_amdgcn_mfma_f32_16x16x32_f16(an, bWn[1][ks], acc[mt][1], 0, 0, 0);
        }
    }
}

// ---- weight prep: fp32 W[l][k][n] -> fp16 Wt[l][n][k] ----
__global__ __launch_bounds__(256) void k_prep(
    const float* __restrict__ lin_w, const float* __restrict__ nb_w,
    f16* __restrict__ Wlt, f16* __restrict__ Wnt)
{
    int id = blockIdx.x * 256 + threadIdx.x;
    int mat = id / 49152;
    int r   = id - mat * 49152;
    int l   = r >> 14;
    int r2  = r & 16383;
    int k   = r2 >> 7;
    int n   = r2 & 127;
    const float* src = mat ? nb_w : lin_w;
    f16*         dst = mat ? Wnt  : Wlt;
    dst[l * 16384 + n * 128 + k] = (f16)src[l * 16384 + k * 128 + n];
}

// ---- conv epilogue: bias+mask, BN partial stats, DIRECT C-layout global store ----
// hn stored as f16 at off = ((blk*4+w)*16 + mt*2+nt)*256 + lane*4 + reg.
__device__ __forceinline__ void conv_epilogue_c(
    f32x4 acc[8][2], const float bsum[2], const float* __restrict__ msk,
    f16* __restrict__ hnb, float* __restrict__ gstats,
    int blk, int wave, int quad, int lane, int slot)
{
    uint2* out2 = (uint2*)hnb;
    float s[2] = {0.f, 0.f}, ss[2] = {0.f, 0.f};
    #pragma unroll
    for (int nt = 0; nt < 2; ++nt) {
        #pragma unroll
        for (int mt = 0; mt < 8; ++mt) {
            f16 v4[4];
            #pragma unroll
            for (int reg = 0; reg < 4; ++reg) {
                int lrow = mt * 16 + quad * 4 + reg;
                float v = (acc[mt][nt][reg] + bsum[nt]) * msk[lrow];
                v4[reg] = (f16)v;
                s[nt] += v; ss[nt] += v * v;
            }
            size_t chunk = ((size_t)blk * 4 + wave) * 16 + mt * 2 + nt;
            out2[chunk * 64 + lane] = *((const uint2*)v4);
        }
    }
    #pragma unroll
    for (int nt = 0; nt < 2; ++nt) {
        s[nt]  += __shfl_xor(s[nt], 16);  s[nt]  += __shfl_xor(s[nt], 32);
        ss[nt] += __shfl_xor(ss[nt], 16); ss[nt] += __shfl_xor(ss[nt], 32);
    }
    if (lane < 16) {
        int colbase = wave * 32;
        #pragma unroll
        for (int nt = 0; nt < 2; ++nt) {
            int col = colbase + nt * 16 + lane;
            atomicAdd(&gstats[slot * 2 * H + col],     s[nt]);
            atomicAdd(&gstats[slot * 2 * H + H + col], ss[nt]);
        }
    }
}

// ---- layer 0 conv: compose h0 = affine(x) in LDS -> conv -> hnb(C-layout) + stats ----
__global__ __launch_bounds__(256) void k_conv0f(
    const float* __restrict__ x, const float* __restrict__ ew,
    const float* __restrict__ eb,
    const f16* __restrict__ Wlt, const f16* __restrict__ Wnt,
    const float* __restrict__ bl, const float* __restrict__ bnb,
    const float* __restrict__ mask,
    f16* __restrict__ hnb, float* __restrict__ gstats)
{
    __shared__ __align__(16) f16 hs[(CNPB + 2) * HS_STRIDE];
    __shared__ float ews[3 * H], msk[CNPB];
    const int t = threadIdx.x, lane = t & 63;
    const int l15 = lane & 15, quad = lane >> 4;
    const int wave = t >> 6;
    const int colbase = wave * 32;
    const int r0 = blockIdx.x * CNPB;
    const int batch = r0 >> 13, n0 = r0 & (NN - 1);

    half8 bWl[2][4], bWn[2][4];
    load_bfrags(Wlt, bWl, colbase, l15, quad);
    load_bfrags(Wnt, bWn, colbase, l15, quad);
    float bsum[2];
    #pragma unroll
    for (int nt = 0; nt < 2; ++nt) {
        int col = colbase + nt * 16 + l15;
        bsum[nt] = bl[col] + bnb[col];
    }
    for (int c = t; c < H; c += 256) {
        ews[c] = ew[c]; ews[H + c] = ew[H + c]; ews[2 * H + c] = eb[c];
    }
    if (t < CNPB) msk[t] = mask[r0 + t];
    __syncthreads();

    for (int i = t; i < (CNPB + 2) * 16; i += 256) {
        int row = i >> 4, g = i & 15;
        int n = (n0 + row - 1 + NN) & (NN - 1);
        const float* xp = x + 2 * ((size_t)batch * NN + n);
        float x0 = xp[0], x1 = xp[1];
        f16 o[8];
        #pragma unroll
        for (int e = 0; e < 8; ++e) {
            int c = g * 8 + e;
            o[e] = (f16)fmaf(x1, ews[H + c], fmaf(x0, ews[c], ews[2 * H + c]));
        }
        *((uint4*)(hs + row * HS_STRIDE + g * 8)) = *((const uint4*)o);
    }
    __syncthreads();

    f32x4 acc[8][2];
    conv_mfma8(hs, bWl, bWn, acc, l15, quad);

    conv_epilogue_c(acc, bsum, msk, hnb, gstats,
                    blockIdx.x, wave, quad, lane, blockIdx.x & (NSLOT - 1));
}

// ---- generic conv (layers 1,2): stage hb tile -> conv -> hnb(C-layout) + stats ----
__global__ __launch_bounds__(256) void k_conv(
    const f16* __restrict__ hb,
    const f16* __restrict__ Wlt, const f16* __restrict__ Wnt,
    const float* __restrict__ bl, const float* __restrict__ bnb,
    const float* __restrict__ mask,
    f16* __restrict__ hnb, float* __restrict__ gstats)
{
    __shared__ __align__(16) f16 hs[(CNPB + 2) * HS_STRIDE];
    __shared__ float msk[CNPB];
    const int t = threadIdx.x, lane = t & 63;
    const int l15 = lane & 15, quad = lane >> 4;
    const int wave = t >> 6;
    const int colbase = wave * 32;
    const int r0 = blockIdx.x * CNPB;
    const int batch = r0 >> 13, n0 = r0 & (NN - 1);

    half8 bWl[2][4], bWn[2][4];
    load_bfrags(Wlt, bWl, colbase, l15, quad);
    load_bfrags(Wnt, bWn, colbase, l15, quad);
    float bsum[2];
    #pragma unroll
    for (int nt = 0; nt < 2; ++nt) {
        int col = colbase + nt * 16 + l15;
        bsum[nt] = bl[col] + bnb[col];
    }
    if (t < CNPB) msk[t] = mask[r0 + t];

    for (int i = t; i < (CNPB + 2) * 16; i += 256) {
        int row = i >> 4, g = i & 15;
        int n = (n0 + row - 1 + NN) & (NN - 1);
        *((uint4*)(hs + row * HS_STRIDE + g * 8)) =
            *((const uint4*)(hb + ((size_t)(batch * NN + n)) * H + g * 8));
    }
    __syncthreads();

    f32x4 acc[8][2];
    conv_mfma8(hs, bWl, bWn, acc, l15, quad);

    conv_epilogue_c(acc, bsum, msk, hnb, gstats,
                    blockIdx.x, wave, quad, lane, blockIdx.x & (NSLOT - 1));
}

// ---- norm core: ingest C-layout hn tile, BN+relu into LDS (standard layout) ----
// Decode of uint4 i (0..2047) within tile: f16 j=i*8; chunk=i>>5; L=(i&31)*2;
// cols c0=w*32+nt*16+(L&15), c0+1; rows mt*16+(L>>4)*4 .. +3.
__device__ __forceinline__ void norm_ingest(
    const f16* __restrict__ hnb, int blk, int t,
    const float* __restrict__ scl_s, const float* __restrict__ sft_s,
    f16* __restrict__ g)
{
    const uint4* src = (const uint4*)hnb + (size_t)blk * 2048;
    for (int i = t; i < 2048; i += 256) {
        uint4 pk = src[i];
        int chunk = i >> 5;
        int L     = (i & 31) * 2;
        int ntv   = chunk & 1;
        int mtv   = (chunk >> 1) & 7;
        int wv    = chunk >> 4;
        int c0    = wv * 32 + ntv * 16 + (L & 15);
        int row0  = mtv * 16 + (L >> 4) * 4;
        float vv[8];
        unpackh8(pk, vv);
        #pragma unroll
        for (int e = 0; e < 8; ++e) {
            int cc = c0 + (e >> 2);
            int rr = row0 + (e & 3);
            float q = fmaxf(fmaf(vv[e], scl_s[cc], sft_s[cc]), 0.f);
            g[rr * HS_STRIDE + cc] = (f16)q;
        }
    }
}

__device__ __forceinline__ void bn_finalize(
    const float* __restrict__ gstats, const float* __restrict__ bn_g,
    const float* __restrict__ bn_b, int t, float* scl_s, float* sft_s)
{
    if (t < H) {
        float s = 0.f, ss = 0.f;
        #pragma unroll
        for (int i = 0; i < NSLOT; ++i) {
            s  += gstats[i * 2 * H + t];
            ss += gstats[i * 2 * H + H + t];
        }
        const float invR = 1.f / (float)RTOT;
        float mean = s * invR;
        float var  = ss * invR - mean * mean;
        float inv  = rsqrtf(var + BNEPS);
        float sc   = bn_g[t] * inv;
        scl_s[t] = sc;
        sft_s[t] = fmaf(-mean, sc, bn_b[t]);
    }
}

// ---- norm0: hb = affine(x) + relu(BN0(hn0)) ----
__global__ __launch_bounds__(256) void k_norm0(
    const float* __restrict__ x, const float* __restrict__ ew,
    const float* __restrict__ eb, const f16* __restrict__ hnb,
    const float* __restrict__ gstats, const float* __restrict__ bn_g,
    const float* __restrict__ bn_b, f16* __restrict__ hb)
{
    __shared__ __align__(16) f16 g[CNPB * HS_STRIDE];
    __shared__ float scl_s[H], sft_s[H], ews[3 * H];
    const int t = threadIdx.x;
    const int blk = blockIdx.x;
    const size_t r0 = (size_t)blk * CNPB;

    bn_finalize(gstats, bn_g, bn_b, t, scl_s, sft_s);
    if (t < H) { ews[t] = ew[t]; ews[H + t] = ew[H + t]; ews[2 * H + t] = eb[t]; }
    __syncthreads();

    norm_ingest(hnb, blk, t, scl_s, sft_s, g);
    __syncthreads();

    for (int i = t; i < 2048; i += 256) {
        int row = i >> 4, gg = i & 15;
        size_t grow = r0 + row;
        float x0 = x[2 * grow], x1 = x[2 * grow + 1];
        uint4 pg = *((const uint4*)(g + row * HS_STRIDE + gg * 8));
        float vg[8], vh[8];
        unpackh8(pg, vg);
        #pragma unroll
        for (int e = 0; e < 8; ++e) {
            int c = gg * 8 + e;
            float h0 = fmaf(x1, ews[H + c], fmaf(x0, ews[c], ews[2 * H + c]));
            vh[e] = h0 + vg[e];
        }
        *((uint4*)(hb + grow * H + gg * 8)) = packh8(vh);
    }
}

// ---- norm (layers 1,2): hb += relu(BN(hn)) ----
__global__ __launch_bounds__(256) void k_norm(
    const f16* __restrict__ hnb, const float* __restrict__ gstats,
    const float* __restrict__ bn_g, const float* __restrict__ bn_b,
    f16* __restrict__ hb)
{
    __shared__ __align__(16) f16 g[CNPB * HS_STRIDE];
    __shared__ float scl_s[H], sft_s[H];
    const int t = threadIdx.x;
    const int blk = blockIdx.x;
    const size_t r0 = (size_t)blk * CNPB;

    bn_finalize(gstats, bn_g, bn_b, t, scl_s, sft_s);
    __syncthreads();

    norm_ingest(hnb, blk, t, scl_s, sft_s, g);
    __syncthreads();

    for (int i = t; i < 2048; i += 256) {
        int row = i >> 4, gg = i & 15;
        size_t grow = r0 + row;
        uint4 ph = *((const uint4*)(hb + grow * H + gg * 8));
        uint4 pg = *((const uint4*)(g + row * HS_STRIDE + gg * 8));
        float vh[8], vg[8];
        unpackh8(ph, vh);
        unpackh8(pg, vg);
        #pragma unroll
        for (int e = 0; e < 8; ++e) vh[e] += vg[e];
        *((uint4*)(hb + grow * H + gg * 8)) = packh8(vh);
    }
}

// ---- MFMA head: out = (relu(h@W1 + b1) @ W2 + b2) * m ----
__global__ __launch_bounds__(256) void k_head(
    const f16* __restrict__ hb, const float* __restrict__ W1,
    const float* __restrict__ b1, const float* __restrict__ W2,
    const float* __restrict__ b2, const float* __restrict__ mask,
    float* __restrict__ out)
{
    __shared__ f16 hs [64 * HS_STRIDE];
    __shared__ f16 w1t[64 * HS_STRIDE];
    const int t    = threadIdx.x;
    const int wave = t >> 6;
    const int lane = t & 63;
    const int l15  = lane & 15;
    const int quad = lane >> 4;
    const int r0   = blockIdx.x * HNPB;

    for (int i = t; i < 64 * 16; i += 256) {
        int row = i >> 4, g = i & 15;
        *((uint4*)(hs + row * HS_STRIDE + g * 8)) =
            *((const uint4*)(hb + (size_t)(r0 + row) * H + g * 8));
    }
    for (int i = t; i < H * 64; i += 256) {
        int k = i >> 6, n = i & 63;
        w1t[n * HS_STRIDE + k] = (f16)W1[i];
    }
    __syncthreads();

    f32x4 acc[4];
    #pragma unroll
    for (int nt = 0; nt < 4; ++nt) acc[nt] = (f32x4){0.f, 0.f, 0.f, 0.f};

    #pragma unroll
    for (int ks = 0; ks < 4; ++ks) {
        half8 a = *((const half8*)(hs + (wave * 16 + l15) * HS_STRIDE + ks * 32 + quad * 8));
        #pragma unroll
        for (int nt = 0; nt < 4; ++nt) {
            half8 b = *((const half8*)(w1t + (nt * 16 + l15) * HS_STRIDE + ks * 32 + quad * 8));
            acc[nt] = __builtin_amdgcn_mfma_f32_16x16x32_f16(a, b, acc[nt], 0, 0, 0);
        }
    }

    float p0[4] = {0,0,0,0}, p1[4] = {0,0,0,0};
    #pragma unroll
    for (int nt = 0; nt < 4; ++nt) {
        int col = nt * 16 + l15;
        float bb = b1[col];
        float wa = W2[2 * col], wb = W2[2 * col + 1];
        #pragma unroll
        for (int reg = 0; reg < 4; ++reg) {
            float v = fmaxf(acc[nt][reg] + bb, 0.f);
            p0[reg] = fmaf(v, wa, p0[reg]);
            p1[reg] = fmaf(v, wb, p1[reg]);
        }
    }
    #pragma unroll
    for (int reg = 0; reg < 4; ++reg) {
        p0[reg] += __shfl_xor(p0[reg], 1); p0[reg] += __shfl_xor(p0[reg], 2);
        p0[reg] += __shfl_xor(p0[reg], 4); p0[reg] += __shfl_xor(p0[reg], 8);
        p1[reg] += __shfl_xor(p1[reg], 1); p1[reg] += __shfl_xor(p1[reg], 2);
        p1[reg] += __shfl_xor(p1[reg], 4); p1[reg] += __shfl_xor(p1[reg], 8);
    }
    if (l15 == 0) {
        #pragma unroll
        for (int reg = 0; reg < 4; ++reg) {
            int gr = r0 + wave * 16 + quad * 4 + reg;
            float m = mask[gr];
            float2 o;
            o.x = (p0[reg] + b2[0]) * m;
            o.y = (p1[reg] + b2[1]) * m;
            *((float2*)(out + 2 * gr)) = o;
        }
    }
}

extern "C" void kernel_launch(void* const* d_in, const int* in_sizes, int n_in,
                              void* d_out, int out_size, void* d_ws, size_t ws_size,
                              hipStream_t stream)
{
    const float* x     = (const float*)d_in[0];
    const float* mask  = (const float*)d_in[1];
    const float* emb_w = (const float*)d_in[2];
    const float* emb_b = (const float*)d_in[3];
    const float* lin_w = (const float*)d_in[4];
    const float* lin_b = (const float*)d_in[5];
    const float* nb_w  = (const float*)d_in[6];
    const float* nb_b  = (const float*)d_in[7];
    const float* bn_g  = (const float*)d_in[8];
    const float* bn_b  = (const float*)d_in[9];
    const float* o1w   = (const float*)d_in[10];
    const float* o1b   = (const float*)d_in[11];
    const float* o2w   = (const float*)d_in[12];
    const float* o2b   = (const float*)d_in[13];
    float* out = (float*)d_out;

    // Workspace: hb (fp16 standard, 64 MiB) + hnb (fp16 C-layout, 64 MiB).
    char* ws = (char*)d_ws;
    f16* hb  = (f16*)ws;
    f16* hnb = (f16*)(ws + (size_t)RTOT * H * 2);

    // d_out scratch (consumed by conv/norm only; k_head never reads d_out).
    float* gst = (float*)d_out;                  // 3 * NSLOT * 2 * H floats
    f16* Wlt = (f16*)((float*)d_out + 65536);    // 3*128*128 fp16
    f16* Wnt = Wlt + NLAYER * H * H;

    hipMemsetAsync(gst, 0, NLAYER * NSLOT * 2 * H * sizeof(float), stream);
    k_prep<<<384, 256, 0, stream>>>(lin_w, nb_w, Wlt, Wnt);

    // layer 0 (h0 composed from x on the fly)
    k_conv0f<<<RTOT / CNPB, 256, 0, stream>>>(
        x, emb_w, emb_b, Wlt, Wnt, lin_b, nb_b, mask, hnb, gst);
    k_norm0<<<RTOT / CNPB, 256, 0, stream>>>(
        x, emb_w, emb_b, hnb, gst, bn_g, bn_b, hb);

    // layers 1, 2
    for (int i = 1; i < NLAYER; ++i) {
        k_conv<<<RTOT / CNPB, 256, 0, stream>>>(
            hb, Wlt + i * H * H, Wnt + i * H * H,
            lin_b + i * H, nb_b + i * H, mask,
            hnb, gst + i * NSLOT * 2 * H);
        k_norm<<<RTOT / CNPB, 256, 0, stream>>>(
            hnb, gst + i * NSLOT * 2 * H, bn_g + i * H, bn_b + i * H, hb);
    }
    k_head<<<RTOT / HNPB, 256, 0, stream>>>(hb, o1w, o1b, o2w, o2b, mask, out);
}